// Round 4
// baseline (48.986 us; speedup 1.0000x reference)
//
#include <hip/hip_runtime.h>
#include <math.h>
#include <float.h>

#define B_ 32
#define N_ 256
#define T_OBS_ 50
#define T_S_ 25
#define D_ 128
#define D_H_ 256
#define P_ 8
#define R_ 4             // rows per block in fused kernel
#define NCH_ 8           // n-chunks in K1
#define NPC_ (N_ / NCH_)      // 32 n per chunk
#define PLANE_ (T_S_ * D_)    // 3200 floats per (b,n)

static constexpr double TWO_PI_D = 6.283185307179586476925286766559;
static constexpr float EPS_F = 1e-4f;

// ---------------------------------------------------------------------------
// K1: partial max over an n-chunk, fully contiguous streaming (R2 winner).
// grid = 32 b * 8 chunks = 256 blocks (1/CU), 800 threads; thread owns one
// float4 of the (t,d) plane; per n-iteration the block reads a contiguous
// 12.8 KB; per block a contiguous 409.6 KB of f_nei.
// ---------------------------------------------------------------------------
__global__ __launch_bounds__(800) void k1_partial(
    const float* __restrict__ f_ego, const float* __restrict__ f_nei,
    float* __restrict__ part) {
  int b = blockIdx.x >> 3;
  int c = blockIdx.x & 7;
  int tid = threadIdx.x;  // 0..799
  int t = tid >> 5;
  int d4 = tid & 31;

  const float4 e =
      *(const float4*)(f_ego + ((size_t)b * T_S_ + t) * D_ + 4 * d4);
  const float* base =
      f_nei + ((size_t)b * N_ + (size_t)c * NPC_) * PLANE_ + 4 * tid;

  float4 m = make_float4(-FLT_MAX, -FLT_MAX, -FLT_MAX, -FLT_MAX);
#pragma unroll 8
  for (int i = 0; i < NPC_; ++i) {
    float4 v = *(const float4*)(base + (size_t)i * PLANE_);
    m.x = fmaxf(m.x, e.x * v.x);
    m.y = fmaxf(m.y, e.y * v.y);
    m.z = fmaxf(m.z, e.z * v.z);
    m.w = fmaxf(m.w, e.w * v.w);
  }
  *(float4*)(part + (size_t)blockIdx.x * PLANE_ + 4 * tid) = m;
}

// ---------------------------------------------------------------------------
// K2: fused combine + MLP + polar histogram + output.
// 200 blocks x 1024 threads (16 waves/block, ~4 waves/SIMD). Thread =
// (k-quarter q = tid>>8, column j = tid&255). Each quarter computes k-slice
// partials (independent unrolled L2 weight loads = deep ILP); partials
// combined in LDS. Weight traffic per block unchanged vs R_=4 mapping.
// ---------------------------------------------------------------------------
__global__ __launch_bounds__(1024) void k2_fused(
    const float* __restrict__ part, const float* __restrict__ W1,
    const float* __restrict__ b1, const float* __restrict__ W2,
    const float* __restrict__ b2, const float* __restrict__ W3,
    const float* __restrict__ b3, const float* __restrict__ x_ego,
    const float* __restrict__ x_nei, const float* __restrict__ Wce,
    const float* __restrict__ bce, float* __restrict__ out) {
  __shared__ float sin_[R_][D_];        // 2 KB
  __shared__ float shp[4][R_][D_H_];    // 16 KB (k-quarter partials; reused)
  __shared__ float sh1[R_][D_H_];       // 4 KB
  __shared__ float sh2[R_][D_H_];       // 4 KB
  __shared__ float f3s[R_][64];         // 1 KB
  __shared__ float cnt[R_][P_], dsum[R_][P_], asum[R_][P_];

  const int tid = threadIdx.x;
  const int row0 = blockIdx.x * R_;
  const int j = tid & 255;
  const int q = tid >> 8;  // 0..3

  if (tid < R_ * P_) {
    (&cnt[0][0])[tid] = 0.f;
    (&dsum[0][0])[tid] = 0.f;
    (&asum[0][0])[tid] = 0.f;
  }

  // ---- combine K1 partials -> sin_ ----
  if (tid < R_ * D_) {
    int r = tid >> 7, d = tid & 127;
    int row = row0 + r;
    int b = row / T_S_, t = row - b * T_S_;
    const float* p = part + (size_t)b * NCH_ * PLANE_ + t * D_ + d;
    float m = -FLT_MAX;
#pragma unroll
    for (int c = 0; c < NCH_; ++c) m = fmaxf(m, p[(size_t)c * PLANE_]);
    sin_[r][d] = m;
  }

  // ---- histogram input loads, hoisted (thread = (row q, neighbor j)) ----
  float2 eg, xn;
  {
    int row = row0 + q;
    int b = row / T_S_, t = row - b * T_S_;
    int tobs = 2 * t;
    eg = *(const float2*)&x_ego[((size_t)b * T_OBS_ + tobs) * 2];
    xn = *(const float2*)&x_nei[(((size_t)b * N_ + j) * T_OBS_ + tobs) * 2];
  }

  const float bb1 = b1[j];
  const float bb2 = b2[j];
  const float bb3 = b3[tid & 63];

  __syncthreads();  // B1: sin_ ready

  // ---- layer 1: 128 -> 256, k-quarter = 32 ----
  {
    float a[R_] = {0.f, 0.f, 0.f, 0.f};
#pragma unroll
    for (int kk = 0; kk < 32; kk += 4) {
      int k = q * 32 + kk;
      float w[4];
#pragma unroll
      for (int u = 0; u < 4; ++u) w[u] = W1[(size_t)(k + u) * D_H_ + j];
#pragma unroll
      for (int rr = 0; rr < R_; ++rr)
#pragma unroll
        for (int u = 0; u < 4; ++u)
          a[rr] = fmaf(sin_[rr][k + u], w[u], a[rr]);
    }
#pragma unroll
    for (int rr = 0; rr < R_; ++rr) shp[q][rr][j] = a[rr];
  }
  __syncthreads();  // B2
  {
    int r = q;
    sh1[r][j] = fmaxf(
        shp[0][r][j] + shp[1][r][j] + shp[2][r][j] + shp[3][r][j] + bb1, 0.f);
  }
  __syncthreads();  // B3: sh1 ready

  // ---- layer 2: 256 -> 256, k-quarter = 64 ----
  {
    float a[R_] = {0.f, 0.f, 0.f, 0.f};
#pragma unroll
    for (int kk = 0; kk < 64; kk += 4) {
      int k = q * 64 + kk;
      float w[4];
#pragma unroll
      for (int u = 0; u < 4; ++u) w[u] = W2[(size_t)(k + u) * D_H_ + j];
#pragma unroll
      for (int rr = 0; rr < R_; ++rr)
#pragma unroll
        for (int u = 0; u < 4; ++u)
          a[rr] = fmaf(sh1[rr][k + u], w[u], a[rr]);
    }
#pragma unroll
    for (int rr = 0; rr < R_; ++rr) shp[q][rr][j] = a[rr];
  }
  __syncthreads();  // B4
  {
    int r = q;
    sh2[r][j] = fmaxf(
        shp[0][r][j] + shp[1][r][j] + shp[2][r][j] + shp[3][r][j] + bb2, 0.f);
  }
  __syncthreads();  // B5: sh2 ready, shp free

  // ---- layer 3: 256 -> 64, k-quarter = 64; plus histogram atomics ----
  {
    int j3 = tid & 63, r3 = (tid >> 6) & 3;
    float acc = 0.f;
#pragma unroll
    for (int kk = 0; kk < 64; kk += 4) {
      int k = q * 64 + kk;
#pragma unroll
      for (int u = 0; u < 4; ++u)
        acc = fmaf(sh2[r3][k + u], W3[(size_t)(k + u) * 64 + j3], acc);
    }
    (&shp[0][0][0])[q * 256 + r3 * 64 + j3] = acc;
  }
  {
    float p0 = xn.x - eg.x;
    float p1 = xn.y - eg.y;
    float dist = sqrtf(p0 * p0 + p1 * p1);
    double angd = atan2((double)p0, (double)p1);
    if (angd < 0.0) angd += TWO_PI_D;
    float ang = (float)angd;
    int pidx = (int)(angd / (TWO_PI_D / (double)P_));
    bool mask = ((fabsf(p0) + fabsf(p1)) != 0.f) && (dist > 0.005f);
    if (mask && pidx >= 0 && pidx < P_) {
      atomicAdd(&cnt[q][pidx], 1.f);
      atomicAdd(&dsum[q][pidx], dist);
      atomicAdd(&asum[q][pidx], ang);
    }
  }
  __syncthreads();  // B6: layer3 partials + histogram done

  if (tid < 256) {
    int r = tid >> 6, j3 = tid & 63;
    const float* sp3 = &shp[0][0][0];
    f3s[r][j3] = fmaxf(sp3[r * 64 + j3] + sp3[256 + r * 64 + j3] +
                           sp3[512 + r * 64 + j3] + sp3[768 + r * 64 + j3] +
                           bb3,
                       0.f);
  }
  __syncthreads();  // B7: f3s ready

  // ---- output: 4 rows x 1024 = 4096 floats, 4 per thread ----
  float* orow = out + (size_t)row0 * (P_ * D_);
#pragma unroll
  for (int ii = 0; ii < 4; ++ii) {
    int idx = tid + ii * 1024;
    int r = idx >> 10;
    int i = idx & 1023;
    int p = i >> 7;
    int c = i & 127;
    float nn = cnt[r][p] + EPS_F;
    float val;
    if (c < 64) {
      val = f3s[r][c] * (cnt[r][p] / nn);
    } else {
      int jj = c - 64;
      val = fmaf(dsum[r][p] / nn, Wce[jj],
                 fmaf(asum[r][p] / nn, Wce[64 + jj], bce[jj]));
      val = fmaxf(val, 0.f);
    }
    orow[idx] = val;
  }
}

// ---------------------------------------------------------------------------
extern "C" void kernel_launch(void* const* d_in, const int* in_sizes, int n_in,
                              void* d_out, int out_size, void* d_ws,
                              size_t ws_size, hipStream_t stream) {
  const float* x_ego = (const float*)d_in[0];   // (32,50,2)
  const float* x_nei = (const float*)d_in[1];   // (32,256,50,2)
  const float* f_ego = (const float*)d_in[2];   // (32,25,128)
  const float* f_nei = (const float*)d_in[3];   // (32,256,25,128)
  const float* W1 = (const float*)d_in[4];      // (128,256)
  const float* b1 = (const float*)d_in[5];
  const float* W2 = (const float*)d_in[6];      // (256,256)
  const float* b2 = (const float*)d_in[7];
  const float* W3 = (const float*)d_in[8];      // (256,64)
  const float* b3 = (const float*)d_in[9];
  const float* Wce = (const float*)d_in[10];    // (2,64)
  const float* bce = (const float*)d_in[11];
  float* out = (float*)d_out;                   // (32,25,8,128)

  float* part = (float*)d_ws;  // 256 * 3200 floats = 3.28 MB

  k1_partial<<<B_ * NCH_, 800, 0, stream>>>(f_ego, f_nei, part);
  k2_fused<<<(B_ * T_S_) / R_, 1024, 0, stream>>>(part, W1, b1, W2, b2, W3,
                                                  b3, x_ego, x_nei, Wce, bce,
                                                  out);
}

// Round 5
// 38.721 us; speedup vs baseline: 1.2651x; 1.2651x over previous
//
#include <hip/hip_runtime.h>
#include <math.h>
#include <float.h>

#define B_ 32
#define N_ 256
#define T_OBS_ 50
#define T_S_ 25
#define D_ 128
#define D_H_ 256
#define P_ 8
#define NCH_ 8                // n-chunks in K1
#define NPC_ (N_ / NCH_)      // 32 n per chunk
#define PLANE_ (T_S_ * D_)    // 3200 floats per (b,n)
#define RB_ 2                 // rows per block in K2

static constexpr double TWO_PI_D = 6.283185307179586476925286766559;
static constexpr float EPS_F = 1e-4f;

// ---------------------------------------------------------------------------
// K1: partial max over an n-chunk, fully contiguous streaming (R2 winner,
// byte-identical). grid = 32 b * 8 chunks = 256 blocks, 800 threads.
// ---------------------------------------------------------------------------
__global__ __launch_bounds__(800) void k1_partial(
    const float* __restrict__ f_ego, const float* __restrict__ f_nei,
    float* __restrict__ part) {
  int b = blockIdx.x >> 3;
  int c = blockIdx.x & 7;
  int tid = threadIdx.x;  // 0..799
  int t = tid >> 5;
  int d4 = tid & 31;

  const float4 e =
      *(const float4*)(f_ego + ((size_t)b * T_S_ + t) * D_ + 4 * d4);
  const float* base =
      f_nei + ((size_t)b * N_ + (size_t)c * NPC_) * PLANE_ + 4 * tid;

  float4 m = make_float4(-FLT_MAX, -FLT_MAX, -FLT_MAX, -FLT_MAX);
#pragma unroll 8
  for (int i = 0; i < NPC_; ++i) {
    float4 v = *(const float4*)(base + (size_t)i * PLANE_);
    m.x = fmaxf(m.x, e.x * v.x);
    m.y = fmaxf(m.y, e.y * v.y);
    m.z = fmaxf(m.z, e.z * v.z);
    m.w = fmaxf(m.w, e.w * v.w);
  }
  *(float4*)(part + (size_t)blockIdx.x * PLANE_ + 4 * tid) = m;
}

// ---------------------------------------------------------------------------
// K2: fused combine + MLP + polar histogram + output, rebuilt for the
// latency regime. 400 blocks x 512 threads, RB_=2 rows/block.
// MLP layers: thread = (k-slice s, column-quad j4); float4 weight loads;
// 8 independent accumulators (2 rows x 4 cols); k-slice partials combined
// through a 16 KB LDS pool.
// ---------------------------------------------------------------------------
__global__ __launch_bounds__(512) void k2_fused(
    const float* __restrict__ part, const float* __restrict__ W1,
    const float* __restrict__ b1, const float* __restrict__ W2,
    const float* __restrict__ b2, const float* __restrict__ W3,
    const float* __restrict__ b3, const float* __restrict__ x_ego,
    const float* __restrict__ x_nei, const float* __restrict__ Wce,
    const float* __restrict__ bce, float* __restrict__ out) {
  __shared__ float spool[4096];     // 16 KB k-slice partials (L1/L2/L3 reuse)
  __shared__ float sin_[RB_][D_];   // 1 KB
  __shared__ float sh1[RB_][D_H_];  // 2 KB
  __shared__ float sh2[RB_][D_H_];  // 2 KB
  __shared__ float f3s[RB_][64];
  __shared__ float cnt[RB_][P_], dsum[RB_][P_], asum[RB_][P_];

  const int tid = threadIdx.x;
  const int row0 = blockIdx.x * RB_;

  if (tid < RB_ * P_) {
    (&cnt[0][0])[tid] = 0.f;
    (&dsum[0][0])[tid] = 0.f;
    (&asum[0][0])[tid] = 0.f;
  }

  // ---- combine K1 partials -> sin_ (256 values, 1 per thread) ----
  if (tid < RB_ * D_) {
    int r = tid >> 7, d = tid & 127;
    int row = row0 + r;
    int b = row / T_S_, t = row - b * T_S_;
    const float* p = part + (size_t)b * NCH_ * PLANE_ + t * D_ + d;
    float m = -FLT_MAX;
#pragma unroll
    for (int c = 0; c < NCH_; ++c) m = fmaxf(m, p[(size_t)c * PLANE_]);
    sin_[r][d] = m;
  }

  // ---- histogram input loads, hoisted (1 item per thread) ----
  float2 eg, xn;
  {
    int r = tid >> 8, n = tid & 255;
    int row = row0 + r;
    int b = row / T_S_, t = row - b * T_S_;
    int tobs = 2 * t;
    eg = *(const float2*)&x_ego[((size_t)b * T_OBS_ + tobs) * 2];
    xn = *(const float2*)&x_nei[(((size_t)b * N_ + n) * T_OBS_ + tobs) * 2];
  }

  const float bb1 = b1[tid & 255];
  const float bb2 = b2[tid & 255];

  __syncthreads();  // B1: sin_ ready

  // ---- layer 1: 128 -> 256. s=tid>>6 (8 slices of 16 k), j4=tid&63 ----
  {
    const int s = tid >> 6, j4 = tid & 63;
    const float4* W1v = (const float4*)W1;
    float a[RB_][4] = {};
#pragma unroll
    for (int kk = 0; kk < 16; ++kk) {
      int k = s * 16 + kk;
      float4 w = W1v[k * 64 + j4];
#pragma unroll
      for (int r = 0; r < RB_; ++r) {
        float x = sin_[r][k];
        a[r][0] = fmaf(x, w.x, a[r][0]);
        a[r][1] = fmaf(x, w.y, a[r][1]);
        a[r][2] = fmaf(x, w.z, a[r][2]);
        a[r][3] = fmaf(x, w.w, a[r][3]);
      }
    }
#pragma unroll
    for (int r = 0; r < RB_; ++r)
      *(float4*)&spool[(s * RB_ + r) * 256 + 4 * j4] =
          make_float4(a[r][0], a[r][1], a[r][2], a[r][3]);
  }
  __syncthreads();  // B2
  {
    int r = tid >> 8, j = tid & 255;
    float sum = bb1;
#pragma unroll
    for (int s = 0; s < 8; ++s) sum += spool[(s * RB_ + r) * 256 + j];
    sh1[r][j] = fmaxf(sum, 0.f);
  }
  __syncthreads();  // B3: sh1 ready

  // ---- layer 2: 256 -> 256. s: 8 slices of 32 k ----
  {
    const int s = tid >> 6, j4 = tid & 63;
    const float4* W2v = (const float4*)W2;
    float a[RB_][4] = {};
#pragma unroll
    for (int kk = 0; kk < 32; ++kk) {
      int k = s * 32 + kk;
      float4 w = W2v[k * 64 + j4];
#pragma unroll
      for (int r = 0; r < RB_; ++r) {
        float x = sh1[r][k];
        a[r][0] = fmaf(x, w.x, a[r][0]);
        a[r][1] = fmaf(x, w.y, a[r][1]);
        a[r][2] = fmaf(x, w.z, a[r][2]);
        a[r][3] = fmaf(x, w.w, a[r][3]);
      }
    }
#pragma unroll
    for (int r = 0; r < RB_; ++r)
      *(float4*)&spool[(s * RB_ + r) * 256 + 4 * j4] =
          make_float4(a[r][0], a[r][1], a[r][2], a[r][3]);
  }
  __syncthreads();  // B4
  {
    int r = tid >> 8, j = tid & 255;
    float sum = bb2;
#pragma unroll
    for (int s = 0; s < 8; ++s) sum += spool[(s * RB_ + r) * 256 + j];
    sh2[r][j] = fmaxf(sum, 0.f);
  }
  __syncthreads();  // B5: sh2 ready, spool free

  // ---- layer 3: 256 -> 64. s3=tid>>4 (32 slices of 8 k), j4=tid&15;
  //      plus histogram atomics (independent work, overlaps) ----
  {
    const int s3 = tid >> 4, j4 = tid & 15;
    const float4* W3v = (const float4*)W3;
    float a[RB_][4] = {};
#pragma unroll
    for (int kk = 0; kk < 8; ++kk) {
      int k = s3 * 8 + kk;
      float4 w = W3v[k * 16 + j4];
#pragma unroll
      for (int r = 0; r < RB_; ++r) {
        float x = sh2[r][k];
        a[r][0] = fmaf(x, w.x, a[r][0]);
        a[r][1] = fmaf(x, w.y, a[r][1]);
        a[r][2] = fmaf(x, w.z, a[r][2]);
        a[r][3] = fmaf(x, w.w, a[r][3]);
      }
    }
#pragma unroll
    for (int r = 0; r < RB_; ++r)
      *(float4*)&spool[(s3 * RB_ + r) * 64 + 4 * j4] =
          make_float4(a[r][0], a[r][1], a[r][2], a[r][3]);
  }
  {
    int r = tid >> 8;
    float p0 = xn.x - eg.x;
    float p1 = xn.y - eg.y;
    float dist = sqrtf(p0 * p0 + p1 * p1);
    double angd = atan2((double)p0, (double)p1);
    if (angd < 0.0) angd += TWO_PI_D;
    float ang = (float)angd;
    int pidx = (int)(angd / (TWO_PI_D / (double)P_));
    bool mask = ((fabsf(p0) + fabsf(p1)) != 0.f) && (dist > 0.005f);
    if (mask && pidx >= 0 && pidx < P_) {
      atomicAdd(&cnt[r][pidx], 1.f);
      atomicAdd(&dsum[r][pidx], dist);
      atomicAdd(&asum[r][pidx], ang);
    }
  }
  __syncthreads();  // B6: layer3 partials + histogram done

  if (tid < RB_ * 64) {
    int r = tid >> 6, j = tid & 63;
    float sum = b3[j];
#pragma unroll
    for (int s = 0; s < 32; ++s) sum += spool[(s * RB_ + r) * 64 + j];
    f3s[r][j] = fmaxf(sum, 0.f);
  }
  __syncthreads();  // B7: f3s ready

  // ---- output: 2 rows x 1024 floats = 512 float4, 1 per thread ----
  {
    int r = tid >> 8, i4 = tid & 255;
    int p = i4 >> 5;
    int c0 = (i4 & 31) * 4;
    float nn = cnt[r][p] + EPS_F;
    float4 v;
    if (c0 < 64) {
      float sc = cnt[r][p] / nn;
      v = make_float4(f3s[r][c0 + 0] * sc, f3s[r][c0 + 1] * sc,
                      f3s[r][c0 + 2] * sc, f3s[r][c0 + 3] * sc);
    } else {
      int jj = c0 - 64;
      float dm = dsum[r][p] / nn;
      float am = asum[r][p] / nn;
      v.x = fmaxf(fmaf(dm, Wce[jj + 0], fmaf(am, Wce[64 + jj + 0], bce[jj + 0])), 0.f);
      v.y = fmaxf(fmaf(dm, Wce[jj + 1], fmaf(am, Wce[64 + jj + 1], bce[jj + 1])), 0.f);
      v.z = fmaxf(fmaf(dm, Wce[jj + 2], fmaf(am, Wce[64 + jj + 2], bce[jj + 2])), 0.f);
      v.w = fmaxf(fmaf(dm, Wce[jj + 3], fmaf(am, Wce[64 + jj + 3], bce[jj + 3])), 0.f);
    }
    *(float4*)(out + (size_t)(row0 + r) * 1024 + 4 * i4) = v;
  }
}

// ---------------------------------------------------------------------------
extern "C" void kernel_launch(void* const* d_in, const int* in_sizes, int n_in,
                              void* d_out, int out_size, void* d_ws,
                              size_t ws_size, hipStream_t stream) {
  const float* x_ego = (const float*)d_in[0];   // (32,50,2)
  const float* x_nei = (const float*)d_in[1];   // (32,256,50,2)
  const float* f_ego = (const float*)d_in[2];   // (32,25,128)
  const float* f_nei = (const float*)d_in[3];   // (32,256,25,128)
  const float* W1 = (const float*)d_in[4];      // (128,256)
  const float* b1 = (const float*)d_in[5];
  const float* W2 = (const float*)d_in[6];      // (256,256)
  const float* b2 = (const float*)d_in[7];
  const float* W3 = (const float*)d_in[8];      // (256,64)
  const float* b3 = (const float*)d_in[9];
  const float* Wce = (const float*)d_in[10];    // (2,64)
  const float* bce = (const float*)d_in[11];
  float* out = (float*)d_out;                   // (32,25,8,128)

  float* part = (float*)d_ws;  // 256 * 3200 floats = 3.28 MB

  k1_partial<<<B_ * NCH_, 800, 0, stream>>>(f_ego, f_nei, part);
  k2_fused<<<(B_ * T_S_) / RB_, 512, 0, stream>>>(part, W1, b1, W2, b2, W3,
                                                  b3, x_ego, x_nei, Wce, bce,
                                                  out);
}